// Round 2
// baseline (2241.568 us; speedup 1.0000x reference)
//
#include <hip/hip_runtime.h>

// Sinkhorn: B=256 batches, N=512, 50 iterations, REG=1.
// Plan:
//   k_makeK:    K = bf16(exp(-cost)), stored in the FIRST HALF OF d_out
//               (128 MB of the 256 MB output buffer; epilogue never reads K).
//   k_sinkhorn: one 1024-thread block per batch runs all 50 iterations with
//               u,v in LDS; K streamed from L2/L3 (128 MB total fits L3).
//               Writes log(u), log(v) to d_ws (1 MB).
//   k_out:      out[b,i,j] = log u[b,i] - cost[b,i,j] + log v[b,j] (streaming).

#define SK_B   256
#define SK_N   512
#define SK_NIT 50

__device__ __forceinline__ unsigned short f2bf_rne(float f) {
    union { float f; unsigned int u; } x; x.f = f;
    unsigned int r = (x.u + 0x7FFFu + ((x.u >> 16) & 1u)) >> 16;
    return (unsigned short)r;
}
__device__ __forceinline__ float bf_lo(unsigned int u) {
    union { unsigned int u; float f; } x; x.u = u << 16; return x.f;
}
__device__ __forceinline__ float bf_hi(unsigned int u) {
    union { unsigned int u; float f; } x; x.u = u & 0xffff0000u; return x.f;
}

__global__ void k_makeK(const float4* __restrict__ cost, ushort4* __restrict__ K, int n4) {
    int stride = gridDim.x * blockDim.x;
    for (int i = blockIdx.x * blockDim.x + threadIdx.x; i < n4; i += stride) {
        float4 c = cost[i];
        ushort4 o;
        o.x = f2bf_rne(__expf(-c.x));
        o.y = f2bf_rne(__expf(-c.y));
        o.z = f2bf_rne(__expf(-c.z));
        o.w = f2bf_rne(__expf(-c.w));
        K[i] = o;
    }
}

// One block per batch. 1024 threads = 16 waves.
// Column pass: thread (w = tid>>6, lane = tid&63) owns cols [lane*8, lane*8+8),
//   accumulates over rows i = w, w+16, ... (fully coalesced: one wave load = one
//   full 1 KB row). Partials reduced across the 16 waves via LDS.
// Row pass: wave w owns rows w, w+16, ...; lane covers its 8 cols; 64-lane
//   shuffle reduction gives the row sum.
__launch_bounds__(1024)
__global__ void k_sinkhorn(const unsigned short* __restrict__ Kg,
                           float* __restrict__ lu, float* __restrict__ lv) {
    const int b = blockIdx.x;
    const uint4* __restrict__ Kb = (const uint4*)(Kg + (size_t)b * SK_N * SK_N);
    __shared__ float u_s[SK_N];
    __shared__ float v_s[SK_N];
    __shared__ float part[16][SK_N];   // 32 KB wave-partial column sums
    const int tid  = threadIdx.x;
    const int lane = tid & 63;
    const int w    = tid >> 6;

    if (tid < SK_N) u_s[tid] = 1.0f / SK_N;
    __syncthreads();

    for (int it = 0; it < SK_NIT; ++it) {
        // ---- column sums: v_j = 1 / sum_i u_i K_ij
        float a0=0.f,a1=0.f,a2=0.f,a3=0.f,a4=0.f,a5=0.f,a6=0.f,a7=0.f;
        for (int i = w; i < SK_N; i += 16) {
            float ui = u_s[i];
            uint4 p = Kb[i * 64 + lane];
            a0 = fmaf(ui, bf_lo(p.x), a0);
            a1 = fmaf(ui, bf_hi(p.x), a1);
            a2 = fmaf(ui, bf_lo(p.y), a2);
            a3 = fmaf(ui, bf_hi(p.y), a3);
            a4 = fmaf(ui, bf_lo(p.z), a4);
            a5 = fmaf(ui, bf_hi(p.z), a5);
            a6 = fmaf(ui, bf_lo(p.w), a6);
            a7 = fmaf(ui, bf_hi(p.w), a7);
        }
        float* pr = &part[w][lane * 8];
        pr[0]=a0; pr[1]=a1; pr[2]=a2; pr[3]=a3;
        pr[4]=a4; pr[5]=a5; pr[6]=a6; pr[7]=a7;
        __syncthreads();
        if (tid < SK_N) {
            float s = 0.f;
            #pragma unroll
            for (int g = 0; g < 16; ++g) s += part[g][tid];
            v_s[tid] = 1.0f / s;
        }
        __syncthreads();

        // ---- row sums: u_i = 1 / sum_j K_ij v_j
        float v0 = v_s[lane*8+0], v1 = v_s[lane*8+1],
              v2 = v_s[lane*8+2], v3 = v_s[lane*8+3],
              v4 = v_s[lane*8+4], v5 = v_s[lane*8+5],
              v6 = v_s[lane*8+6], v7 = v_s[lane*8+7];
        for (int i = w; i < SK_N; i += 16) {
            uint4 p = Kb[i * 64 + lane];
            float s;
            s = v0 * bf_lo(p.x);
            s = fmaf(v1, bf_hi(p.x), s);
            s = fmaf(v2, bf_lo(p.y), s);
            s = fmaf(v3, bf_hi(p.y), s);
            s = fmaf(v4, bf_lo(p.z), s);
            s = fmaf(v5, bf_hi(p.z), s);
            s = fmaf(v6, bf_lo(p.w), s);
            s = fmaf(v7, bf_hi(p.w), s);
            #pragma unroll
            for (int off = 32; off >= 1; off >>= 1)
                s += __shfl_xor(s, off, 64);
            if (lane == 0) u_s[i] = 1.0f / s;
        }
        __syncthreads();
    }

    if (tid < SK_N) {
        lu[b * SK_N + tid] = __logf(u_s[tid]);
        lv[b * SK_N + tid] = __logf(v_s[tid]);
    }
}

__global__ void k_out(const float4* __restrict__ cost, const float* __restrict__ lu,
                      const float4* __restrict__ lv4, float4* __restrict__ out, int n4) {
    int idx = blockIdx.x * blockDim.x + threadIdx.x;
    if (idx >= n4) return;
    int bb  = idx >> 16;            // element e = idx*4; b = e>>18
    int row = (idx >> 7) & (SK_N - 1);
    int j4  = idx & 127;
    float  l_u = lu[bb * SK_N + row];
    float4 lvv = lv4[bb * 128 + j4];
    float4 c   = cost[idx];
    float4 o;
    o.x = l_u - c.x + lvv.x;
    o.y = l_u - c.y + lvv.y;
    o.z = l_u - c.z + lvv.z;
    o.w = l_u - c.w + lvv.w;
    out[idx] = o;
}

extern "C" void kernel_launch(void* const* d_in, const int* in_sizes, int n_in,
                              void* d_out, int out_size, void* d_ws, size_t ws_size,
                              hipStream_t stream) {
    const float* cost = (const float*)d_in[0];
    float* out = (float*)d_out;

    // bf16 K lives in the first half of d_out (128 MB of 256 MB); epilogue
    // reads only cost/lu/lv, so overwriting d_out at the end is safe.
    unsigned short* K = (unsigned short*)d_out;
    float* lu = (float*)d_ws;                 // 256*512 floats = 512 KB
    float* lv = lu + SK_B * SK_N;             // 512 KB

    const int n4 = SK_B * SK_N * SK_N / 4;    // 16,777,216 float4 groups

    k_makeK<<<8192, 256, 0, stream>>>((const float4*)cost, (ushort4*)K, n4);
    k_sinkhorn<<<SK_B, 1024, 0, stream>>>(K, lu, lv);
    k_out<<<n4 / 256, 256, 0, stream>>>((const float4*)cost, lu,
                                        (const float4*)lv, (float4*)out, n4);
}